// Round 1
// baseline (2008.787 us; speedup 1.0000x reference)
//
#include <hip/hip_runtime.h>
#include <stdint.h>

#define L_LAYERS 4
#define BATCH 8
#define PHH 24
#define PWW 24
#define PP (PHH*PWW)        // 576
#define DD 1024
#define ROWS (BATCH*PP)     // 4608
#define OH 336
#define OW 336
#define NTILES 72           // 4608/64  (64-col max groups)
#define NCOMBO 12           // 3 radii x 4 layers
// 256x256 tiling for the pipelined GEMM
#define TT2 18              // 4608/256
#define NPAIRS2 (TT2*(TT2+1)/2)   // 171 upper-triangle tiles
#define TOTBLK2 (NPAIRS2*NCOMBO)  // 2052
#define XQ (TOTBLK2/8)      // 256
#define XR (TOTBLK2%8)      // 4
#define PRESCALE 1024.0f    // fp8 quant prescale (power of 2, exact)
#define INV_PRESCALE2_X2 (1.f/524288.f)   // 2 / PRESCALE^2

typedef __attribute__((ext_vector_type(8))) int i32x8;
typedef __attribute__((ext_vector_type(4))) float f32x4;

// float -> bf16 round-to-nearest-even (raw bits)
__device__ __forceinline__ unsigned int f2bf(float f) {
  unsigned int u = __float_as_uint(f);
  return (u + 0x7FFFu + ((u >> 16) & 1u)) >> 16;
}

__device__ __forceinline__ float bflo(unsigned int w) {
  return __uint_as_float(w << 16);
}
__device__ __forceinline__ float bfhi(unsigned int w) {
  return __uint_as_float(w & 0xFFFF0000u);
}

// expand 4 bf16 (8 bytes) to 4 floats
__device__ __forceinline__ void load4bf(float* d, const unsigned short* p) {
  const uint2 u = *(const uint2*)p;
  d[0] = bflo(u.x); d[1] = bfhi(u.x);
  d[2] = bflo(u.y); d[3] = bfhi(u.y);
}

// async global->LDS, 16B per lane. LDS dest is wave-uniform base + lane*16
// (base = first ACTIVE lane) -> never predicate individual lanes off.
__device__ __forceinline__ void async16(const void* g, void* l) {
  __builtin_amdgcn_global_load_lds(
      (const __attribute__((address_space(1))) void*)(size_t)(uintptr_t)g,
      (__attribute__((address_space(3))) void*)(uint32_t)(uintptr_t)l,
      16, 0, 0);
}

// ---------------------------------------------------------------------------
// Kernel 1: sliding-window pool, BOTH axes (reads feat exactly once).
// ---------------------------------------------------------------------------
__global__ __launch_bounds__(256) void pool_kernel(
    const float* __restrict__ feat,      // [L][B][PP][DD]
    unsigned short* __restrict__ h3,     // [L][ROWS][DD] bf16 bits (3x3 sum)
    unsigned short* __restrict__ h5) {   // [L][ROWS][DD] bf16 bits (5x5 sum)
  const int dch = blockIdx.x;            // 64-dim chunk
  const int b = blockIdx.y;
  const int l = blockIdx.z >> 1;
  const int half = blockIdx.z & 1;
  const int py0 = half * 12, py1 = py0 + 11;
  const int t = threadIdx.x;
  const int pxg = t >> 5;                // 0..7
  const int d2 = t & 31;                 // float2 index within 64-dim chunk

  __shared__ float ring[5][24 * 64];     // 30 KB
  __shared__ unsigned int v3p[24 * 32];  // 3 KB packed bf16 pairs
  __shared__ unsigned int v5p[24 * 32];  // 3 KB

  const float* fb = feat + ((size_t)l * BATCH + b) * PP * DD + dch * 64 + d2 * 2;

  for (int yy = py0 - 2; yy <= py0 + 1; ++yy) {
    if (yy < 0) continue;
    #pragma unroll
    for (int i = 0; i < 3; ++i) {
      int px = i * 8 + pxg;
      *(float2*)&ring[yy % 5][px * 64 + d2 * 2] =
          *(const float2*)(fb + (size_t)(yy * PWW + px) * DD);
    }
  }
  for (int py = py0; py <= py1; ++py) {
    const int yl = py + 2;
    if (yl < PHH) {
      __syncthreads();
      #pragma unroll
      for (int i = 0; i < 3; ++i) {
        int px = i * 8 + pxg;
        *(float2*)&ring[yl % 5][px * 64 + d2 * 2] =
            *(const float2*)(fb + (size_t)(yl * PWW + px) * DD);
      }
    }
    __syncthreads();
    #pragma unroll
    for (int i = 0; i < 3; ++i) {
      int px = i * 8 + pxg;
      float s3x = 0.f, s3y = 0.f, s5x = 0.f, s5y = 0.f;
      #pragma unroll
      for (int dy = -2; dy <= 2; ++dy) {
        int yy = py + dy;
        if (yy < 0 || yy >= PHH) continue;
        float2 v = *(const float2*)&ring[yy % 5][px * 64 + d2 * 2];
        s5x += v.x; s5y += v.y;
        if (dy >= -1 && dy <= 1) { s3x += v.x; s3y += v.y; }
      }
      v3p[px * 32 + d2] = f2bf(s3x) | (f2bf(s3y) << 16);
      v5p[px * 32 + d2] = f2bf(s5x) | (f2bf(s5y) << 16);
    }
    __syncthreads();
    #pragma unroll
    for (int i = 0; i < 3; ++i) {
      int px = i * 8 + pxg;
      float h3x = 0.f, h3y = 0.f, h5x = 0.f, h5y = 0.f;
      #pragma unroll
      for (int dx = -2; dx <= 2; ++dx) {
        int xx = px + dx;
        if (xx < 0 || xx >= PWW) continue;
        unsigned int w5 = v5p[xx * 32 + d2];
        h5x += bflo(w5); h5y += bfhi(w5);
        if (dx >= -1 && dx <= 1) {
          unsigned int w3 = v3p[xx * 32 + d2];
          h3x += bflo(w3); h3y += bfhi(w3);
        }
      }
      const size_t idx =
          ((size_t)l * ROWS + b * PP + py * PWW + px) * DD + dch * 64 + d2 * 2;
      *(unsigned int*)&h3[idx] = f2bf(h3x) | (f2bf(h3y) << 16);
      *(unsigned int*)&h5[idx] = f2bf(h5x) | (f2bf(h5y) << 16);
    }
  }
}

// ---------------------------------------------------------------------------
// Kernel 2: normalize + fp8(e4m3) quantize (x PRESCALE).
// ---------------------------------------------------------------------------
__global__ __launch_bounds__(256) void quant_kernel(
    const float* __restrict__ feat,
    const unsigned short* __restrict__ h3,
    const unsigned short* __restrict__ h5,
    unsigned char* __restrict__ nf_all) {    // [NCOMBO][ROWS][DD] fp8
  const int row = blockIdx.x;
  const int l = blockIdx.y;
  const int t = threadIdx.x;
  const int lane = t & 63, w = t >> 6;
  const int d0 = t * 4;
  const size_t lro = ((size_t)l * ROWS + row) * DD + d0;

  float s1[4], s3[4], s5[4];
  {
    const float4 f = *(const float4*)(feat + lro);
    s1[0] = f.x; s1[1] = f.y; s1[2] = f.z; s1[3] = f.w;
  }
  load4bf(s3, h3 + lro);
  load4bf(s5, h5 + lro);

  float q1 = 0.f, q3 = 0.f, q5 = 0.f;
  #pragma unroll
  for (int j = 0; j < 4; ++j) {
    q1 += s1[j]*s1[j]; q3 += s3[j]*s3[j]; q5 += s5[j]*s5[j];
  }
  #pragma unroll
  for (int off = 32; off > 0; off >>= 1) {
    q1 += __shfl_down(q1, off);
    q3 += __shfl_down(q3, off);
    q5 += __shfl_down(q5, off);
  }
  __shared__ float red[4][3];
  if (lane == 0) { red[w][0] = q1; red[w][1] = q3; red[w][2] = q5; }
  __syncthreads();
  const float rn1 = rsqrtf(red[0][0] + red[1][0] + red[2][0] + red[3][0]) * PRESCALE;
  const float rn3 = rsqrtf(red[0][1] + red[1][1] + red[2][1] + red[3][1]) * PRESCALE;
  const float rn5 = rsqrtf(red[0][2] + red[1][2] + red[2][2] + red[3][2]) * PRESCALE;

  const size_t ro = (size_t)row * DD + d0;
  unsigned int o;
  o = __builtin_amdgcn_cvt_pk_fp8_f32(s1[0]*rn1, s1[1]*rn1, 0, false);
  o = __builtin_amdgcn_cvt_pk_fp8_f32(s1[2]*rn1, s1[3]*rn1, o, true);
  *(unsigned int*)(nf_all + (size_t)(0*L_LAYERS + l) * ROWS * DD + ro) = o;
  o = __builtin_amdgcn_cvt_pk_fp8_f32(s3[0]*rn3, s3[1]*rn3, 0, false);
  o = __builtin_amdgcn_cvt_pk_fp8_f32(s3[2]*rn3, s3[3]*rn3, o, true);
  *(unsigned int*)(nf_all + (size_t)(1*L_LAYERS + l) * ROWS * DD + ro) = o;
  o = __builtin_amdgcn_cvt_pk_fp8_f32(s5[0]*rn5, s5[1]*rn5, 0, false);
  o = __builtin_amdgcn_cvt_pk_fp8_f32(s5[2]*rn5, s5[3]*rn5, o, true);
  *(unsigned int*)(nf_all + (size_t)(2*L_LAYERS + l) * ROWS * DD + ro) = o;
}

// ---------------------------------------------------------------------------
// Kernel 3: symmetric Gram GEMM, MX-fp8, 256x256 tile, 8 waves (4m x 2n),
// double-buffered LDS (128 KB), two-phase pipelined K-loop (T3+T4+T5):
//   per K-tile: {ds_read frags, prefetch next tile, raw barrier, lgkmcnt(0),
//   setprio(1) MFMA x16 setprio(0), barrier} x2 phases; single vmcnt(0)
//   drain per K-tile via __syncthreads at iteration end (prefetch issued
//   1-2 phases earlier -> latency hidden under MFMA clusters).
// 32B-granule XOR swizzle (j ^ (row&6)) kept: lane's 32 K-bytes contiguous,
// single i32x8 deref. Accumulation order over K unchanged -> numerics
// identical to the 128^2 version.
// Output format unchanged: row-max per 64-col group + transposed col-max
// into part[combo][row][NTILES].
// ---------------------------------------------------------------------------
__device__ __forceinline__ void stage_tile(const unsigned char* __restrict__ g,
                                           unsigned char* l, int t) {
  // 256 rows x 128 B = 2048 16B-chunks; 512 threads -> 4 chunks each.
  #pragma unroll
  for (int i = 0; i < 4; ++i) {
    int c = i * 512 + t;
    int row = c >> 3, j = c & 7;
    int gg = j ^ (row & 6);
    async16(g + (size_t)row * DD + gg * 16, l + c * 16);
  }
}

__global__ __launch_bounds__(512, 2) void gemm_max_kernel(
    const unsigned char* __restrict__ nf_all,   // [NCOMBO][ROWS][DD] fp8
    float* __restrict__ part) {                 // [NCOMBO][ROWS][NTILES]
  // bijective XCD-aware swizzle (TOTBLK2 % 8 != 0 -> m204 form)
  const int bid = blockIdx.x;
  const int xcd = bid & 7;
  const int slot = (xcd < XR ? xcd * (XQ + 1) : XR * (XQ + 1) + (xcd - XR) * XQ)
                   + (bid >> 3);
  const int combo = slot / NPAIRS2;
  int rem = slot % NPAIRS2;
  int it = 0;
  while (rem >= TT2 - it) { rem -= TT2 - it; ++it; }
  const int jt = it + rem;
  const int row0 = it * 256;
  const int col0 = jt * 256;

  // dead-tile check: both tiles fully inside the same image -> never read
  {
    const bool inA = (row0 / PP) == ((row0 + 255) / PP);
    const bool inB = (col0 / PP) == ((col0 + 255) / PP);
    if (inA && inB && (row0 / PP) == (col0 / PP)) return;
  }

  __shared__ unsigned char AsBuf[2][256 * 128];   // 2 x 32 KB
  __shared__ unsigned char BsBuf[2][256 * 128];   // 2 x 32 KB

  const int t = threadIdx.x;
  const int lane = t & 63;
  const int wave = t >> 6;       // 0..7
  const int wm = wave >> 1;      // 0..3 : 64-row slice
  const int wn = wave & 1;       // 0..1 : 128-col slice

  const unsigned char* nf = nf_all + (size_t)combo * ROWS * DD;
  float* partialL = part + (size_t)combo * ROWS * NTILES;

  const f32x4 zero = {0.f, 0.f, 0.f, 0.f};
  f32x4 acc[4][8];
  #pragma unroll
  for (int m = 0; m < 4; ++m)
    #pragma unroll
    for (int n = 0; n < 8; ++n) acc[m][n] = zero;

  const unsigned char* gA = nf + (size_t)row0 * DD;
  const unsigned char* gB = nf + (size_t)col0 * DD;

  // lane-constant LDS fragment offset: 32B granule (2q) ^ (r15 & 6)
  const int r15 = lane & 15;
  const int loff = ((((lane >> 4) << 1) ^ (r15 & 6)) << 4);
  const int aRowOff = (wm * 64 + r15) * 128 + loff;
  const int bRowOff = (wn * 128 + r15) * 128 + loff;

  // prologue: stage K-tile 0 into buffer 0, full drain
  stage_tile(gA, AsBuf[0], t);
  stage_tile(gB, BsBuf[0], t);
  asm volatile("s_waitcnt vmcnt(0)" ::: "memory");
  __builtin_amdgcn_s_barrier();

  int cur = 0;
  for (int kt = 0; kt < DD / 128; ++kt) {
    const unsigned char* Ab = AsBuf[cur] + aRowOff;
    const unsigned char* Bb = BsBuf[cur] + bRowOff;

    // ---------------- phase A : n = 0..3 ----------------
    const i32x8 a0 = *(const i32x8*)(Ab +    0);
    const i32x8 a1 = *(const i32x8*)(Ab + 2048);
    const i32x8 a2 = *(const i32x8*)(Ab + 4096);
    const i32x8 a3 = *(const i32x8*)(Ab + 6144);
    {
      const i32x8 b0 = *(const i32x8*)(Bb +    0);
      const i32x8 b1 = *(const i32x8*)(Bb + 2048);
      const i32x8 b2 = *(const i32x8*)(Bb + 4096);
      const i32x8 b3 = *(const i32x8*)(Bb + 6144);
      if (kt < DD / 128 - 1)
        stage_tile(gA + (kt + 1) * 128, AsBuf[cur ^ 1], t);   // prefetch A
      asm volatile("" ::: "memory");
      __builtin_amdgcn_s_barrier();
      asm volatile("s_waitcnt lgkmcnt(0)" ::: "memory");
      __builtin_amdgcn_sched_barrier(0);
      __builtin_amdgcn_s_setprio(1);
      acc[0][0] = __builtin_amdgcn_mfma_scale_f32_16x16x128_f8f6f4(a0, b0, acc[0][0], 0, 0, 0, 0x7F7F7F7F, 0, 0x7F7F7F7F);
      acc[1][0] = __builtin_amdgcn_mfma_scale_f32_16x16x128_f8f6f4(a1, b0, acc[1][0], 0, 0, 0, 0x7F7F7F7F, 0, 0x7F7F7F7F);
      acc[2][0] = __builtin_amdgcn_mfma_scale_f32_16x16x128_f8f6f4(a2, b0, acc[2][0], 0, 0, 0, 0x7F7F7F7F, 0, 0x7F7F7F7F);
      acc[3][0] = __builtin_amdgcn_mfma_scale_f32_16x16x128_f8f6f4(a3, b0, acc[3][0], 0, 0, 0, 0x7F7F7F7F, 0, 0x7F7F7F7F);
      acc[0][1] = __builtin_amdgcn_mfma_scale_f32_16x16x128_f8f6f4(a0, b1, acc[0][1], 0, 0, 0, 0x7F7F7F7F, 0, 0x7F7F7F7F);
      acc[1][1] = __builtin_amdgcn_mfma_scale_f32_16x16x128_f8f6f4(a1, b1, acc[1][1], 0, 0, 0, 0x7F7F7F7F, 0, 0x7F7F7F7F);
      acc[2][1] = __builtin_amdgcn_mfma_scale_f32_16x16x128_f8f6f4(a2, b1, acc[2][1], 0, 0, 0, 0x7F7F7F7F, 0, 0x7F7F7F7F);
      acc[3][1] = __builtin_amdgcn_mfma_scale_f32_16x16x128_f8f6f4(a3, b1, acc[3][1], 0, 0, 0, 0x7F7F7F7F, 0, 0x7F7F7F7F);
      acc[0][2] = __builtin_amdgcn_mfma_scale_f32_16x16x128_f8f6f4(a0, b2, acc[0][2], 0, 0, 0, 0x7F7F7F7F, 0, 0x7F7F7F7F);
      acc[1][2] = __builtin_amdgcn_mfma_scale_f32_16x16x128_f8f6f4(a1, b2, acc[1][2], 0, 0, 0, 0x7F7F7F7F, 0, 0x7F7F7F7F);
      acc[2][2] = __builtin_amdgcn_mfma_scale_f32_16x16x128_f8f6f4(a2, b2, acc[2][2], 0, 0, 0, 0x7F7F7F7F, 0, 0x7F7F7F7F);
      acc[3][2] = __builtin_amdgcn_mfma_scale_f32_16x16x128_f8f6f4(a3, b2, acc[3][2], 0, 0, 0, 0x7F7F7F7F, 0, 0x7F7F7F7F);
      acc[0][3] = __builtin_amdgcn_mfma_scale_f32_16x16x128_f8f6f4(a0, b3, acc[0][3], 0, 0, 0, 0x7F7F7F7F, 0, 0x7F7F7F7F);
      acc[1][3] = __builtin_amdgcn_mfma_scale_f32_16x16x128_f8f6f4(a1, b3, acc[1][3], 0, 0, 0, 0x7F7F7F7F, 0, 0x7F7F7F7F);
      acc[2][3] = __builtin_amdgcn_mfma_scale_f32_16x16x128_f8f6f4(a2, b3, acc[2][3], 0, 0, 0, 0x7F7F7F7F, 0, 0x7F7F7F7F);
      acc[3][3] = __builtin_amdgcn_mfma_scale_f32_16x16x128_f8f6f4(a3, b3, acc[3][3], 0, 0, 0, 0x7F7F7F7F, 0, 0x7F7F7F7F);
      __builtin_amdgcn_s_setprio(0);
      asm volatile("" ::: "memory");
      __builtin_amdgcn_s_barrier();
    }

    // ---------------- phase B : n = 4..7 ----------------
    {
      const i32x8 b4 = *(const i32x8*)(Bb +  8192);
      const i32x8 b5 = *(const i32x8*)(Bb + 10240);
      const i32x8 b6 = *(const i32x8*)(Bb + 12288);
      const i32x8 b7 = *(const i32x8*)(Bb + 14336);
      if (kt < DD / 128 - 1)
        stage_tile(gB + (kt + 1) * 128, BsBuf[cur ^ 1], t);   // prefetch B
      asm volatile("" ::: "memory");
      __builtin_amdgcn_s_barrier();
      asm volatile("s_waitcnt lgkmcnt(0)" ::: "memory");
      __builtin_amdgcn_sched_barrier(0);
      __builtin_amdgcn_s_setprio(1);
      acc[0][4] = __builtin_amdgcn_mfma_scale_f32_16x16x128_f8f6f4(a0, b4, acc[0][4], 0, 0, 0, 0x7F7F7F7F, 0, 0x7F7F7F7F);
      acc[1][4] = __builtin_amdgcn_mfma_scale_f32_16x16x128_f8f6f4(a1, b4, acc[1][4], 0, 0, 0, 0x7F7F7F7F, 0, 0x7F7F7F7F);
      acc[2][4] = __builtin_amdgcn_mfma_scale_f32_16x16x128_f8f6f4(a2, b4, acc[2][4], 0, 0, 0, 0x7F7F7F7F, 0, 0x7F7F7F7F);
      acc[3][4] = __builtin_amdgcn_mfma_scale_f32_16x16x128_f8f6f4(a3, b4, acc[3][4], 0, 0, 0, 0x7F7F7F7F, 0, 0x7F7F7F7F);
      acc[0][5] = __builtin_amdgcn_mfma_scale_f32_16x16x128_f8f6f4(a0, b5, acc[0][5], 0, 0, 0, 0x7F7F7F7F, 0, 0x7F7F7F7F);
      acc[1][5] = __builtin_amdgcn_mfma_scale_f32_16x16x128_f8f6f4(a1, b5, acc[1][5], 0, 0, 0, 0x7F7F7F7F, 0, 0x7F7F7F7F);
      acc[2][5] = __builtin_amdgcn_mfma_scale_f32_16x16x128_f8f6f4(a2, b5, acc[2][5], 0, 0, 0, 0x7F7F7F7F, 0, 0x7F7F7F7F);
      acc[3][5] = __builtin_amdgcn_mfma_scale_f32_16x16x128_f8f6f4(a3, b5, acc[3][5], 0, 0, 0, 0x7F7F7F7F, 0, 0x7F7F7F7F);
      acc[0][6] = __builtin_amdgcn_mfma_scale_f32_16x16x128_f8f6f4(a0, b6, acc[0][6], 0, 0, 0, 0x7F7F7F7F, 0, 0x7F7F7F7F);
      acc[1][6] = __builtin_amdgcn_mfma_scale_f32_16x16x128_f8f6f4(a1, b6, acc[1][6], 0, 0, 0, 0x7F7F7F7F, 0, 0x7F7F7F7F);
      acc[2][6] = __builtin_amdgcn_mfma_scale_f32_16x16x128_f8f6f4(a2, b6, acc[2][6], 0, 0, 0, 0x7F7F7F7F, 0, 0x7F7F7F7F);
      acc[3][6] = __builtin_amdgcn_mfma_scale_f32_16x16x128_f8f6f4(a3, b6, acc[3][6], 0, 0, 0, 0x7F7F7F7F, 0, 0x7F7F7F7F);
      acc[0][7] = __builtin_amdgcn_mfma_scale_f32_16x16x128_f8f6f4(a0, b7, acc[0][7], 0, 0, 0, 0x7F7F7F7F, 0, 0x7F7F7F7F);
      acc[1][7] = __builtin_amdgcn_mfma_scale_f32_16x16x128_f8f6f4(a1, b7, acc[1][7], 0, 0, 0, 0x7F7F7F7F, 0, 0x7F7F7F7F);
      acc[2][7] = __builtin_amdgcn_mfma_scale_f32_16x16x128_f8f6f4(a2, b7, acc[2][7], 0, 0, 0, 0x7F7F7F7F, 0, 0x7F7F7F7F);
      acc[3][7] = __builtin_amdgcn_mfma_scale_f32_16x16x128_f8f6f4(a3, b7, acc[3][7], 0, 0, 0, 0x7F7F7F7F, 0, 0x7F7F7F7F);
      __builtin_amdgcn_s_setprio(0);
    }

    // single full drain per K-tile: next tile's prefetch (8 loads) completes
    // here, having been in flight across 1-2 MFMA phases.
    __syncthreads();
    cur ^= 1;
  }

  // C/D layout: col = lane&15, row = (lane>>4)*4 + reg (shape-determined)
  // Row-max per 64-col group: this wave's 128 cols = groups jt*4+wn*2+{0,1}.
  #pragma unroll
  for (int m = 0; m < 4; ++m) {
    #pragma unroll
    for (int g = 0; g < 4; ++g) {
      #pragma unroll
      for (int h = 0; h < 2; ++h) {
        float v = fmaxf(fmaxf(acc[m][4*h+0][g], acc[m][4*h+1][g]),
                        fmaxf(acc[m][4*h+2][g], acc[m][4*h+3][g]));
        v = fmaxf(v, __shfl_xor(v, 1));
        v = fmaxf(v, __shfl_xor(v, 2));
        v = fmaxf(v, __shfl_xor(v, 4));
        v = fmaxf(v, __shfl_xor(v, 8));
        if ((lane & 15) == 0) {
          int row = row0 + wm * 64 + m * 16 + (lane >> 4) * 4 + g;
          partialL[(size_t)row * NTILES + jt * 4 + wn * 2 + h] = v;
        }
      }
    }
  }
  // Col-max over this wave's 64 rows (64-row group it*4+wm), transposed.
  if (it != jt) {
    #pragma unroll
    for (int n = 0; n < 8; ++n) {
      float v = -1e30f;
      #pragma unroll
      for (int m = 0; m < 4; ++m)
        #pragma unroll
        for (int g = 0; g < 4; ++g) v = fmaxf(v, acc[m][n][g]);
      v = fmaxf(v, __shfl_xor(v, 16));
      v = fmaxf(v, __shfl_xor(v, 32));
      if (lane < 16) {
        int col = col0 + wn * 128 + n * 16 + lane;
        partialL[(size_t)col * NTILES + it * 4 + wm] = v;
      }
    }
  }
}

// ---------------------------------------------------------------------------
// Kernel 4: per row: for each of 12 combos, max over 9 q-groups per image c,
// d-transform (undo fp8 prescale), top-2 smallest over c != b; sum -> scores.
// ---------------------------------------------------------------------------
__global__ __launch_bounds__(256) void reduce_topk_kernel(
    const float* __restrict__ part,      // [NCOMBO][ROWS][NTILES]
    float* __restrict__ scores) {        // [ROWS]
  const int row = blockIdx.x * 256 + threadIdx.x;
  if (row >= ROWS) return;
  const int b = row / PP;
  float sum = 0.f;
  for (int k = 0; k < NCOMBO; ++k) {
    const float* pr = part + ((size_t)k * ROWS + row) * NTILES;
    float d1 = 1e30f, d2 = 1e30f;
    #pragma unroll
    for (int c = 0; c < BATCH; ++c) {
      if (c == b) continue;
      float md = pr[c * 9];
      #pragma unroll
      for (int q = 1; q < 9; ++q) md = fmaxf(md, pr[c * 9 + q]);
      float d = sqrtf(fmaxf(2.f - md * INV_PRESCALE2_X2, 0.f));
      if (d < d1) { d2 = d1; d1 = d; }
      else if (d < d2) { d2 = d; }
    }
    sum += 0.5f * (d1 + d2);
  }
  scores[row] = sum;
}

// ---------------------------------------------------------------------------
// Kernel 5 (fused): blocks 0..3527 = bilinear (align_corners) 24x24 -> 336x336
// scaled 1/12; blocks 3528..3535 = scores_image[b] = max_p scores[b,p] / 12.
// ---------------------------------------------------------------------------
__global__ __launch_bounds__(256) void final_kernel(
    const float* __restrict__ scores, float* __restrict__ out) {
  const int bid = blockIdx.x;
  const int t = threadIdx.x;
  if (bid < (BATCH * OH * OW) / 256) {
    const int idx = bid * 256 + t;
    const int b = idx / (OH * OW);
    const int rem = idx % (OH * OW);
    const int y = rem / OW, x = rem % OW;
    const float sc = (float)(23.0 / 335.0);
    const float ys = y * sc, xs = x * sc;
    const int y0 = (int)floorf(ys), x0 = (int)floorf(xs);
    const float wy = ys - (float)y0, wx = xs - (float)x0;
    const int y1 = min(y0 + 1, PHH - 1), x1 = min(x0 + 1, PWW - 1);
    const float* sb = scores + b * PP;
    const float f00 = sb[y0 * PWW + x0], f01 = sb[y0 * PWW + x1];
    const float f10 = sb[y1 * PWW + x0], f11 = sb[y1 * PWW + x1];
    const float v = f00 * (1.f - wy) * (1.f - wx) + f01 * (1.f - wy) * wx +
                    f10 * wy * (1.f - wx) + f11 * wy * wx;
    out[8 + idx] = v * (1.f / 12.f);
  } else {
    const int b = bid - (BATCH * OH * OW) / 256;
    float m = -1e30f;
    for (int p = t; p < PP; p += 256) m = fmaxf(m, scores[b * PP + p]);
    #pragma unroll
    for (int off = 32; off > 0; off >>= 1) m = fmaxf(m, __shfl_down(m, off));
    __shared__ float red[4];
    if ((t & 63) == 0) red[t >> 6] = m;
    __syncthreads();
    if (t == 0)
      out[b] = fmaxf(fmaxf(red[0], red[1]), fmaxf(red[2], red[3])) * (1.f / 12.f);
  }
}

// ---------------------------------------------------------------------------
extern "C" void kernel_launch(void* const* d_in, const int* in_sizes, int n_in,
                              void* d_out, int out_size, void* d_ws, size_t ws_size,
                              hipStream_t stream) {
  const float* feat = (const float*)d_in[0];     // [4][8][576][1024] f32
  float* out = (float*)d_out;                    // [8] ++ [8][336][336]
  char* ws = (char*)d_ws;

  // workspace layout (~148 MB of ~302 MB)
  const size_t NF_BYTES   = (size_t)NCOMBO * ROWS * DD;            // 56,623,104 (fp8)
  const size_t PART_BYTES = (size_t)NCOMBO * ROWS * NTILES * 4;    // 15,925,248
  const size_t SCR_BYTES  = (size_t)ROWS * 4;                      //     18,432
  const size_t H_BYTES    = (size_t)L_LAYERS * ROWS * DD * 2;      // 37,748,736
  unsigned char*  nf_all = (unsigned char*)ws;
  float*          part   = (float*)(ws + NF_BYTES);
  float*          scr    = (float*)(ws + NF_BYTES + PART_BYTES);
  unsigned short* h3     = (unsigned short*)(ws + NF_BYTES + PART_BYTES + SCR_BYTES);
  unsigned short* h5     = (unsigned short*)(ws + NF_BYTES + PART_BYTES + SCR_BYTES + H_BYTES);

  pool_kernel<<<dim3(16, BATCH, L_LAYERS * 2), 256, 0, stream>>>(feat, h3, h5);
  quant_kernel<<<dim3(ROWS, L_LAYERS), 256, 0, stream>>>(feat, h3, h5, nf_all);
  gemm_max_kernel<<<TOTBLK2, 512, 0, stream>>>(nf_all, part);
  reduce_topk_kernel<<<(ROWS + 255) / 256, 256, 0, stream>>>(part, scr);
  final_kernel<<<(BATCH * OH * OW) / 256 + BATCH, 256, 0, stream>>>(scr, out);
}

// Round 2
// 1967.603 us; speedup vs baseline: 1.0209x; 1.0209x over previous
//
#include <hip/hip_runtime.h>
#include <stdint.h>

#define L_LAYERS 4
#define BATCH 8
#define PHH 24
#define PWW 24
#define PP (PHH*PWW)        // 576
#define DD 1024
#define ROWS (BATCH*PP)     // 4608
#define OH 336
#define OW 336
#define NTILES 72           // 4608/64  (64-col max groups)
#define NCOMBO 12           // 3 radii x 4 layers
// 256x256 tiling for the pipelined GEMM
#define TT2 18              // 4608/256
#define NPAIRS2 (TT2*(TT2+1)/2)   // 171 upper-triangle tiles
#define TOTBLK2 (NPAIRS2*NCOMBO)  // 2052
#define XQ (TOTBLK2/8)      // 256
#define XR (TOTBLK2%8)      // 4
#define PRESCALE 1024.0f    // fp8 quant prescale (power of 2, exact)
#define INV_PRESCALE2_X2 (1.f/524288.f)   // 2 / PRESCALE^2

typedef __attribute__((ext_vector_type(8))) int i32x8;
typedef __attribute__((ext_vector_type(4))) float f32x4;

// float -> bf16 round-to-nearest-even (raw bits)
__device__ __forceinline__ unsigned int f2bf(float f) {
  unsigned int u = __float_as_uint(f);
  return (u + 0x7FFFu + ((u >> 16) & 1u)) >> 16;
}

__device__ __forceinline__ float bflo(unsigned int w) {
  return __uint_as_float(w << 16);
}
__device__ __forceinline__ float bfhi(unsigned int w) {
  return __uint_as_float(w & 0xFFFF0000u);
}

// expand 4 bf16 (8 bytes) to 4 floats
__device__ __forceinline__ void load4bf(float* d, const unsigned short* p) {
  const uint2 u = *(const uint2*)p;
  d[0] = bflo(u.x); d[1] = bfhi(u.x);
  d[2] = bflo(u.y); d[3] = bfhi(u.y);
}

// async global->LDS, 16B per lane. LDS dest is wave-uniform base + lane*16
// (base = first ACTIVE lane) -> never predicate individual lanes off.
__device__ __forceinline__ void async16(const void* g, void* l) {
  __builtin_amdgcn_global_load_lds(
      (const __attribute__((address_space(1))) void*)(size_t)(uintptr_t)g,
      (__attribute__((address_space(3))) void*)(uint32_t)(uintptr_t)l,
      16, 0, 0);
}

// ---------------------------------------------------------------------------
// Kernel 1: sliding-window pool, BOTH axes (reads feat exactly once).
// ---------------------------------------------------------------------------
__global__ __launch_bounds__(256) void pool_kernel(
    const float* __restrict__ feat,      // [L][B][PP][DD]
    unsigned short* __restrict__ h3,     // [L][ROWS][DD] bf16 bits (3x3 sum)
    unsigned short* __restrict__ h5) {   // [L][ROWS][DD] bf16 bits (5x5 sum)
  const int dch = blockIdx.x;            // 64-dim chunk
  const int b = blockIdx.y;
  const int l = blockIdx.z >> 1;
  const int half = blockIdx.z & 1;
  const int py0 = half * 12, py1 = py0 + 11;
  const int t = threadIdx.x;
  const int pxg = t >> 5;                // 0..7
  const int d2 = t & 31;                 // float2 index within 64-dim chunk

  __shared__ float ring[5][24 * 64];     // 30 KB
  __shared__ unsigned int v3p[24 * 32];  // 3 KB packed bf16 pairs
  __shared__ unsigned int v5p[24 * 32];  // 3 KB

  const float* fb = feat + ((size_t)l * BATCH + b) * PP * DD + dch * 64 + d2 * 2;

  for (int yy = py0 - 2; yy <= py0 + 1; ++yy) {
    if (yy < 0) continue;
    #pragma unroll
    for (int i = 0; i < 3; ++i) {
      int px = i * 8 + pxg;
      *(float2*)&ring[yy % 5][px * 64 + d2 * 2] =
          *(const float2*)(fb + (size_t)(yy * PWW + px) * DD);
    }
  }
  for (int py = py0; py <= py1; ++py) {
    const int yl = py + 2;
    if (yl < PHH) {
      __syncthreads();
      #pragma unroll
      for (int i = 0; i < 3; ++i) {
        int px = i * 8 + pxg;
        *(float2*)&ring[yl % 5][px * 64 + d2 * 2] =
            *(const float2*)(fb + (size_t)(yl * PWW + px) * DD);
      }
    }
    __syncthreads();
    #pragma unroll
    for (int i = 0; i < 3; ++i) {
      int px = i * 8 + pxg;
      float s3x = 0.f, s3y = 0.f, s5x = 0.f, s5y = 0.f;
      #pragma unroll
      for (int dy = -2; dy <= 2; ++dy) {
        int yy = py + dy;
        if (yy < 0 || yy >= PHH) continue;
        float2 v = *(const float2*)&ring[yy % 5][px * 64 + d2 * 2];
        s5x += v.x; s5y += v.y;
        if (dy >= -1 && dy <= 1) { s3x += v.x; s3y += v.y; }
      }
      v3p[px * 32 + d2] = f2bf(s3x) | (f2bf(s3y) << 16);
      v5p[px * 32 + d2] = f2bf(s5x) | (f2bf(s5y) << 16);
    }
    __syncthreads();
    #pragma unroll
    for (int i = 0; i < 3; ++i) {
      int px = i * 8 + pxg;
      float h3x = 0.f, h3y = 0.f, h5x = 0.f, h5y = 0.f;
      #pragma unroll
      for (int dx = -2; dx <= 2; ++dx) {
        int xx = px + dx;
        if (xx < 0 || xx >= PWW) continue;
        unsigned int w5 = v5p[xx * 32 + d2];
        h5x += bflo(w5); h5y += bfhi(w5);
        if (dx >= -1 && dx <= 1) {
          unsigned int w3 = v3p[xx * 32 + d2];
          h3x += bflo(w3); h3y += bfhi(w3);
        }
      }
      const size_t idx =
          ((size_t)l * ROWS + b * PP + py * PWW + px) * DD + dch * 64 + d2 * 2;
      *(unsigned int*)&h3[idx] = f2bf(h3x) | (f2bf(h3y) << 16);
      *(unsigned int*)&h5[idx] = f2bf(h5x) | (f2bf(h5y) << 16);
    }
  }
}

// ---------------------------------------------------------------------------
// Kernel 2: normalize + fp8(e4m3) quantize (x PRESCALE).
// ---------------------------------------------------------------------------
__global__ __launch_bounds__(256) void quant_kernel(
    const float* __restrict__ feat,
    const unsigned short* __restrict__ h3,
    const unsigned short* __restrict__ h5,
    unsigned char* __restrict__ nf_all) {    // [NCOMBO][ROWS][DD] fp8
  const int row = blockIdx.x;
  const int l = blockIdx.y;
  const int t = threadIdx.x;
  const int lane = t & 63, w = t >> 6;
  const int d0 = t * 4;
  const size_t lro = ((size_t)l * ROWS + row) * DD + d0;

  float s1[4], s3[4], s5[4];
  {
    const float4 f = *(const float4*)(feat + lro);
    s1[0] = f.x; s1[1] = f.y; s1[2] = f.z; s1[3] = f.w;
  }
  load4bf(s3, h3 + lro);
  load4bf(s5, h5 + lro);

  float q1 = 0.f, q3 = 0.f, q5 = 0.f;
  #pragma unroll
  for (int j = 0; j < 4; ++j) {
    q1 += s1[j]*s1[j]; q3 += s3[j]*s3[j]; q5 += s5[j]*s5[j];
  }
  #pragma unroll
  for (int off = 32; off > 0; off >>= 1) {
    q1 += __shfl_down(q1, off);
    q3 += __shfl_down(q3, off);
    q5 += __shfl_down(q5, off);
  }
  __shared__ float red[4][3];
  if (lane == 0) { red[w][0] = q1; red[w][1] = q3; red[w][2] = q5; }
  __syncthreads();
  const float rn1 = rsqrtf(red[0][0] + red[1][0] + red[2][0] + red[3][0]) * PRESCALE;
  const float rn3 = rsqrtf(red[0][1] + red[1][1] + red[2][1] + red[3][1]) * PRESCALE;
  const float rn5 = rsqrtf(red[0][2] + red[1][2] + red[2][2] + red[3][2]) * PRESCALE;

  const size_t ro = (size_t)row * DD + d0;
  unsigned int o;
  o = __builtin_amdgcn_cvt_pk_fp8_f32(s1[0]*rn1, s1[1]*rn1, 0, false);
  o = __builtin_amdgcn_cvt_pk_fp8_f32(s1[2]*rn1, s1[3]*rn1, o, true);
  *(unsigned int*)(nf_all + (size_t)(0*L_LAYERS + l) * ROWS * DD + ro) = o;
  o = __builtin_amdgcn_cvt_pk_fp8_f32(s3[0]*rn3, s3[1]*rn3, 0, false);
  o = __builtin_amdgcn_cvt_pk_fp8_f32(s3[2]*rn3, s3[3]*rn3, o, true);
  *(unsigned int*)(nf_all + (size_t)(1*L_LAYERS + l) * ROWS * DD + ro) = o;
  o = __builtin_amdgcn_cvt_pk_fp8_f32(s5[0]*rn5, s5[1]*rn5, 0, false);
  o = __builtin_amdgcn_cvt_pk_fp8_f32(s5[2]*rn5, s5[3]*rn5, o, true);
  *(unsigned int*)(nf_all + (size_t)(2*L_LAYERS + l) * ROWS * DD + ro) = o;
}

// ---------------------------------------------------------------------------
// Kernel 3: symmetric Gram GEMM, MX-fp8, 256x256 tile, 8 waves (4m x 2n),
// double-buffered LDS as FOUR NAMED arrays (A0/A1/B0/B1 -> compile-time
// disjoint, no runtime-indexed buffer state), one __syncthreads per K-tile.
// Round-1 post-mortem: 2.2 GB scratch round-trip (WRITE_SIZE) = acc-quadrant
// spill from holding 4 a + 8 b operand vectors live across pinned phase
// boundaries at the 256-unified-VGPR budget. This version caps liveness:
//   - b operands loaded one at a time inside the MFMA loop
//   - single mid-tile sched_barrier(0) stops hoisting of b4..b7 reads
//   - staging addresses collapsed to ONE per-lane base per matrix
//     (swizzle identity: row&6 == (t>>3)&6 for all 4 chunks)
// Schedule per K-tile (T3 minimum-2-phase): stageA(next) -> a-reads ->
// 16 MFMA -> stageB(next) -> 16 MFMA -> __syncthreads (drain lands after
// 16-32 MFMAs of cover). Accumulation order over K unchanged -> numerics
// identical (round-1 passed with identical absmax).
// ---------------------------------------------------------------------------
__device__ __forceinline__ void gemm_step(
    const unsigned char* Acur, const unsigned char* Bcur,   // LDS read base + frag offset
    unsigned char* Anext, unsigned char* Bnext,             // LDS stage dest base + t*16
    const unsigned char* gAn, const unsigned char* gBn,     // per-lane global src (next tile)
    bool doStage, f32x4 (&acc)[4][8]) {
  // issue A prefetch first (maximal lead time)
  if (doStage) {
    #pragma unroll
    for (int i = 0; i < 4; ++i) async16(gAn + i * 65536, Anext + i * 8192);
  }
  __builtin_amdgcn_sched_barrier(0);
  const i32x8 a0 = *(const i32x8*)(Acur +    0);
  const i32x8 a1 = *(const i32x8*)(Acur + 2048);
  const i32x8 a2 = *(const i32x8*)(Acur + 4096);
  const i32x8 a3 = *(const i32x8*)(Acur + 6144);
  #pragma unroll
  for (int n = 0; n < 4; ++n) {
    const i32x8 b = *(const i32x8*)(Bcur + n * 2048);
    acc[0][n] = __builtin_amdgcn_mfma_scale_f32_16x16x128_f8f6f4(a0, b, acc[0][n], 0, 0, 0, 0x7F7F7F7F, 0, 0x7F7F7F7F);
    acc[1][n] = __builtin_amdgcn_mfma_scale_f32_16x16x128_f8f6f4(a1, b, acc[1][n], 0, 0, 0, 0x7F7F7F7F, 0, 0x7F7F7F7F);
    acc[2][n] = __builtin_amdgcn_mfma_scale_f32_16x16x128_f8f6f4(a2, b, acc[2][n], 0, 0, 0, 0x7F7F7F7F, 0, 0x7F7F7F7F);
    acc[3][n] = __builtin_amdgcn_mfma_scale_f32_16x16x128_f8f6f4(a3, b, acc[3][n], 0, 0, 0, 0x7F7F7F7F, 0, 0x7F7F7F7F);
  }
  // liveness fence: b0..b3 dead here; b4..b7 not yet hoisted
  __builtin_amdgcn_sched_barrier(0);
  if (doStage) {
    #pragma unroll
    for (int i = 0; i < 4; ++i) async16(gBn + i * 65536, Bnext + i * 8192);
  }
  #pragma unroll
  for (int n = 4; n < 8; ++n) {
    const i32x8 b = *(const i32x8*)(Bcur + n * 2048);
    acc[0][n] = __builtin_amdgcn_mfma_scale_f32_16x16x128_f8f6f4(a0, b, acc[0][n], 0, 0, 0, 0x7F7F7F7F, 0, 0x7F7F7F7F);
    acc[1][n] = __builtin_amdgcn_mfma_scale_f32_16x16x128_f8f6f4(a1, b, acc[1][n], 0, 0, 0, 0x7F7F7F7F, 0, 0x7F7F7F7F);
    acc[2][n] = __builtin_amdgcn_mfma_scale_f32_16x16x128_f8f6f4(a2, b, acc[2][n], 0, 0, 0, 0x7F7F7F7F, 0, 0x7F7F7F7F);
    acc[3][n] = __builtin_amdgcn_mfma_scale_f32_16x16x128_f8f6f4(a3, b, acc[3][n], 0, 0, 0, 0x7F7F7F7F, 0, 0x7F7F7F7F);
  }
  // one full drain per K-tile: prefetch has had 16-32 MFMAs in flight
  __syncthreads();
}

__global__ __launch_bounds__(512, 2) void gemm_max_kernel(
    const unsigned char* __restrict__ nf_all,   // [NCOMBO][ROWS][DD] fp8
    float* __restrict__ part) {                 // [NCOMBO][ROWS][NTILES]
  // bijective XCD-aware swizzle (TOTBLK2 % 8 != 0 -> m204 form)
  const int bid = blockIdx.x;
  const int xcd = bid & 7;
  const int slot = (xcd < XR ? xcd * (XQ + 1) : XR * (XQ + 1) + (xcd - XR) * XQ)
                   + (bid >> 3);
  const int combo = slot / NPAIRS2;
  int rem = slot % NPAIRS2;
  int it = 0;
  while (rem >= TT2 - it) { rem -= TT2 - it; ++it; }
  const int jt = it + rem;
  const int row0 = it * 256;
  const int col0 = jt * 256;

  // dead-tile check: both tiles fully inside the same image -> never read
  {
    const bool inA = (row0 / PP) == ((row0 + 255) / PP);
    const bool inB = (col0 / PP) == ((col0 + 255) / PP);
    if (inA && inB && (row0 / PP) == (col0 / PP)) return;
  }

  __shared__ unsigned char A0[256 * 128];   // 32 KB each, 128 KB total
  __shared__ unsigned char A1[256 * 128];
  __shared__ unsigned char B0[256 * 128];
  __shared__ unsigned char B1[256 * 128];

  const int t = threadIdx.x;
  const int lane = t & 63;
  const int wave = t >> 6;       // 0..7
  const int wm = wave >> 1;      // 0..3 : 64-row slice
  const int wn = wave & 1;       // 0..1 : 128-col slice

  const unsigned char* nf = nf_all + (size_t)combo * ROWS * DD;
  float* partialL = part + (size_t)combo * ROWS * NTILES;

  const f32x4 zero = {0.f, 0.f, 0.f, 0.f};
  f32x4 acc[4][8];
  #pragma unroll
  for (int m = 0; m < 4; ++m)
    #pragma unroll
    for (int n = 0; n < 8; ++n) acc[m][n] = zero;

  // staging: chunk i (i=0..3), this thread handles 16B-chunk c = i*512+t:
  //   row = i*64 + (t>>3), slot j = t&7, global granule g = j ^ (row&6).
  // Since (i*64+r)&6 == r&6, ONE per-lane base covers all chunks:
  const int r = t >> 3;
  const int gg = (t & 7) ^ (r & 6);
  const unsigned char* gAs = nf + (size_t)row0 * DD + (size_t)r * DD + gg * 16;
  const unsigned char* gBs = nf + (size_t)col0 * DD + (size_t)r * DD + gg * 16;
  const int ldst = t * 16;       // LDS dest base offset (+ i*8192 per chunk)

  // lane-constant LDS fragment offset: 32B granule (2q) ^ (r15 & 6)
  const int r15 = lane & 15;
  const int loff = ((((lane >> 4) << 1) ^ (r15 & 6)) << 4);
  const int aRowOff = (wm * 64 + r15) * 128 + loff;
  const int bRowOff = (wn * 128 + r15) * 128 + loff;

  // prologue: stage K-tile 0 into A0/B0, full drain
  #pragma unroll
  for (int i = 0; i < 4; ++i) async16(gAs + i * 65536, &A0[ldst + i * 8192]);
  #pragma unroll
  for (int i = 0; i < 4; ++i) async16(gBs + i * 65536, &B0[ldst + i * 8192]);
  __syncthreads();

  // main loop: 8 K-tiles, unrolled x2 over named buffers
  #pragma unroll
  for (int kk = 0; kk < 4; ++kk) {
    // even tile 2kk: compute A0/B0, prefetch tile 2kk+1 -> A1/B1
    gemm_step(A0 + aRowOff, B0 + bRowOff, &A1[ldst], &B1[ldst],
              gAs + (2 * kk + 1) * 128, gBs + (2 * kk + 1) * 128,
              true, acc);
    // odd tile 2kk+1: compute A1/B1, prefetch tile 2kk+2 -> A0/B0
    gemm_step(A1 + aRowOff, B1 + bRowOff, &A0[ldst], &B0[ldst],
              gAs + (2 * kk + 2) * 128, gBs + (2 * kk + 2) * 128,
              kk < 3, acc);
  }

  // C/D layout: col = lane&15, row = (lane>>4)*4 + reg (shape-determined)
  // Row-max per 64-col group: this wave's 128 cols = groups jt*4+wn*2+{0,1}.
  #pragma unroll
  for (int m = 0; m < 4; ++m) {
    #pragma unroll
    for (int g = 0; g < 4; ++g) {
      #pragma unroll
      for (int h = 0; h < 2; ++h) {
        float v = fmaxf(fmaxf(acc[m][4*h+0][g], acc[m][4*h+1][g]),
                        fmaxf(acc[m][4*h+2][g], acc[m][4*h+3][g]));
        v = fmaxf(v, __shfl_xor(v, 1));
        v = fmaxf(v, __shfl_xor(v, 2));
        v = fmaxf(v, __shfl_xor(v, 4));
        v = fmaxf(v, __shfl_xor(v, 8));
        if ((lane & 15) == 0) {
          int row = row0 + wm * 64 + m * 16 + (lane >> 4) * 4 + g;
          partialL[(size_t)row * NTILES + jt * 4 + wn * 2 + h] = v;
        }
      }
    }
  }
  // Col-max over this wave's 64 rows (64-row group it*4+wm), transposed.
  if (it != jt) {
    #pragma unroll
    for (int n = 0; n < 8; ++n) {
      float v = -1e30f;
      #pragma unroll
      for (int m = 0; m < 4; ++m)
        #pragma unroll
        for (int g = 0; g < 4; ++g) v = fmaxf(v, acc[m][n][g]);
      v = fmaxf(v, __shfl_xor(v, 16));
      v = fmaxf(v, __shfl_xor(v, 32));
      if (lane < 16) {
        int col = col0 + wn * 128 + n * 16 + lane;
        partialL[(size_t)col * NTILES + it * 4 + wm] = v;
      }
    }
  }
}

// ---------------------------------------------------------------------------
// Kernel 4: per row: for each of 12 combos, max over 9 q-groups per image c,
// d-transform (undo fp8 prescale), top-2 smallest over c != b; sum -> scores.
// ---------------------------------------------------------------------------
__global__ __launch_bounds__(256) void reduce_topk_kernel(
    const float* __restrict__ part,      // [NCOMBO][ROWS][NTILES]
    float* __restrict__ scores) {        // [ROWS]
  const int row = blockIdx.x * 256 + threadIdx.x;
  if (row >= ROWS) return;
  const int b = row / PP;
  float sum = 0.f;
  for (int k = 0; k < NCOMBO; ++k) {
    const float* pr = part + ((size_t)k * ROWS + row) * NTILES;
    float d1 = 1e30f, d2 = 1e30f;
    #pragma unroll
    for (int c = 0; c < BATCH; ++c) {
      if (c == b) continue;
      float md = pr[c * 9];
      #pragma unroll
      for (int q = 1; q < 9; ++q) md = fmaxf(md, pr[c * 9 + q]);
      float d = sqrtf(fmaxf(2.f - md * INV_PRESCALE2_X2, 0.f));
      if (d < d1) { d2 = d1; d1 = d; }
      else if (d < d2) { d2 = d; }
    }
    sum += 0.5f * (d1 + d2);
  }
  scores[row] = sum;
}

// ---------------------------------------------------------------------------
// Kernel 5 (fused): blocks 0..3527 = bilinear (align_corners) 24x24 -> 336x336
// scaled 1/12; blocks 3528..3535 = scores_image[b] = max_p scores[b,p] / 12.
// ---------------------------------------------------------------------------
__global__ __launch_bounds__(256) void final_kernel(
    const float* __restrict__ scores, float* __restrict__ out) {
  const int bid = blockIdx.x;
  const int t = threadIdx.x;
  if (bid < (BATCH * OH * OW) / 256) {
    const int idx = bid * 256 + t;
    const int b = idx / (OH * OW);
    const int rem = idx % (OH * OW);
    const int y = rem / OW, x = rem % OW;
    const float sc = (float)(23.0 / 335.0);
    const float ys = y * sc, xs = x * sc;
    const int y0 = (int)floorf(ys), x0 = (int)floorf(xs);
    const float wy = ys - (float)y0, wx = xs - (float)x0;
    const int y1 = min(y0 + 1, PHH - 1), x1 = min(x0 + 1, PWW - 1);
    const float* sb = scores + b * PP;
    const float f00 = sb[y0 * PWW + x0], f01 = sb[y0 * PWW + x1];
    const float f10 = sb[y1 * PWW + x0], f11 = sb[y1 * PWW + x1];
    const float v = f00 * (1.f - wy) * (1.f - wx) + f01 * (1.f - wy) * wx +
                    f10 * wy * (1.f - wx) + f11 * wy * wx;
    out[8 + idx] = v * (1.f / 12.f);
  } else {
    const int b = bid - (BATCH * OH * OW) / 256;
    float m = -1e30f;
    for (int p = t; p < PP; p += 256) m = fmaxf(m, scores[b * PP + p]);
    #pragma unroll
    for (int off = 32; off > 0; off >>= 1) m = fmaxf(m, __shfl_down(m, off));
    __shared__ float red[4];
    if ((t & 63) == 0) red[t >> 6] = m;
    __syncthreads();
    if (t == 0)
      out[b] = fmaxf(fmaxf(red[0], red[1]), fmaxf(red[2], red[3])) * (1.f / 12.f);
  }
}

// ---------------------------------------------------------------------------
extern "C" void kernel_launch(void* const* d_in, const int* in_sizes, int n_in,
                              void* d_out, int out_size, void* d_ws, size_t ws_size,
                              hipStream_t stream) {
  const float* feat = (const float*)d_in[0];     // [4][8][576][1024] f32
  float* out = (float*)d_out;                    // [8] ++ [8][336][336]
  char* ws = (char*)d_ws;

  // workspace layout (~148 MB of ~302 MB)
  const size_t NF_BYTES   = (size_t)NCOMBO * ROWS * DD;            // 56,623,104 (fp8)
  const size_t PART_BYTES = (size_t)NCOMBO * ROWS * NTILES * 4;    // 15,925,248
  const size_t SCR_BYTES  = (size_t)ROWS * 4;                      //     18,432
  const size_t H_BYTES    = (size_t)L_LAYERS * ROWS * DD * 2;      // 37,748,736
  unsigned char*  nf_all = (unsigned char*)ws;
  float*          part   = (float*)(ws + NF_BYTES);
  float*          scr    = (float*)(ws + NF_BYTES + PART_BYTES);
  unsigned short* h3     = (unsigned short*)(ws + NF_BYTES + PART_BYTES + SCR_BYTES);
  unsigned short* h5     = (unsigned short*)(ws + NF_BYTES + PART_BYTES + SCR_BYTES + H_BYTES);

  pool_kernel<<<dim3(16, BATCH, L_LAYERS * 2), 256, 0, stream>>>(feat, h3, h5);
  quant_kernel<<<dim3(ROWS, L_LAYERS), 256, 0, stream>>>(feat, h3, h5, nf_all);
  gemm_max_kernel<<<TOTBLK2, 512, 0, stream>>>(nf_all, part);
  reduce_topk_kernel<<<(ROWS + 255) / 256, 256, 0, stream>>>(part, scr);
  final_kernel<<<(BATCH * OH * OW) / 256 + BATCH, 256, 0, stream>>>(scr, out);
}